// Round 8
// baseline (1072.834 us; speedup 1.0000x reference)
//
#include <hip/hip_runtime.h>
#include <hip/hip_fp16.h>

#define N_NODES 100000
#define N_EDGES 1600000
#define N_REL 4

// ---------------------------------------------------------------------------
// fp32 -> fp16 table conversion (x4 vectorized)
// ---------------------------------------------------------------------------
__global__ __launch_bounds__(256) void cvt_kernel(const float* __restrict__ in,
                                                  __half* __restrict__ out,
                                                  int n4) {
  int i = blockIdx.x * 256 + threadIdx.x;
  if (i >= n4) return;
  float4 v = ((const float4*)in)[i];
  __half2* o = (__half2*)(out + (long)i * 4);
  o[0] = __floats2half2_rn(v.x, v.y);
  o[1] = __floats2half2_rn(v.z, v.w);
}

// ---------------------------------------------------------------------------
// CSR build with DETERMINISTIC, GLOBALLY MONOTONE offsets:
//   count -> blocksum -> scan(blocksums) -> alloc(off=global excl scan) -> fill
// Monotone off[] makes CSR positions of consecutive segments contiguous, so
// the layer kernel can sweep a block's positions as one flat range.
// ---------------------------------------------------------------------------
__global__ __launch_bounds__(256) void count_kernel(const int* __restrict__ dst,
                                                    const int* __restrict__ et,
                                                    int* __restrict__ cnt,
                                                    int E, int N) {
  int e = blockIdx.x * 256 + threadIdx.x;
  if (e >= E) return;
  atomicAdd(&cnt[et[e] * N + dst[e]], 1);
}

__global__ __launch_bounds__(256) void blocksum_kernel(
    const int* __restrict__ cnt, int* __restrict__ bsum, int RN) {
  __shared__ int s[256];
  int i = blockIdx.x * 256 + threadIdx.x;
  s[threadIdx.x] = (i < RN) ? cnt[i] : 0;
  __syncthreads();
  for (int d = 128; d > 0; d >>= 1) {
    if (threadIdx.x < d) s[threadIdx.x] += s[threadIdx.x + d];
    __syncthreads();
  }
  if (threadIdx.x == 0) bsum[blockIdx.x] = s[0];
}

__global__ __launch_bounds__(256) void scanb_kernel(const int* __restrict__ bsum,
                                                    int* __restrict__ bbase,
                                                    int nB) {
  __shared__ int s[256];
  __shared__ int carry;
  if (threadIdx.x == 0) carry = 0;
  __syncthreads();
  for (int base = 0; base < nB; base += 256) {
    int i = base + threadIdx.x;
    int v = (i < nB) ? bsum[i] : 0;
    s[threadIdx.x] = v;
    __syncthreads();
    for (int d = 1; d < 256; d <<= 1) {
      int t = (threadIdx.x >= d) ? s[threadIdx.x - d] : 0;
      __syncthreads();
      s[threadIdx.x] += t;
      __syncthreads();
    }
    if (i < nB) bbase[i] = carry + s[threadIdx.x] - v;  // exclusive
    __syncthreads();
    if (threadIdx.x == 255) carry += s[255];
    __syncthreads();
  }
}

__global__ __launch_bounds__(256) void alloc_kernel(
    const int* __restrict__ cnt, const int* __restrict__ bbase,
    int* __restrict__ off, int* __restrict__ cur, int RN, int E) {
  __shared__ int s[256];
  int i = blockIdx.x * 256 + threadIdx.x;
  int c = (i < RN) ? cnt[i] : 0;
  s[threadIdx.x] = c;
  __syncthreads();
  for (int d = 1; d < 256; d <<= 1) {
    int t = (threadIdx.x >= d) ? s[threadIdx.x - d] : 0;
    __syncthreads();
    s[threadIdx.x] += t;
    __syncthreads();
  }
  if (i < RN) {
    int ex = bbase[blockIdx.x] + s[threadIdx.x] - c;
    off[i] = ex;
    cur[i] = ex;
  }
  if (i == 0) off[RN] = E;  // sentinel
}

__global__ __launch_bounds__(256) void fill_kernel(
    const int* __restrict__ src, const int* __restrict__ dst,
    const int* __restrict__ et, int* __restrict__ cur, int* __restrict__ eidx,
    int* __restrict__ ndst, int E, int N) {
  int e = blockIdx.x * 256 + threadIdx.x;
  if (e >= E) return;
  int d = dst[e];
  int seg = et[e] * N + d;
  int pos = atomicAdd(&cur[seg], 1);
  eidx[pos] = src[e];
  ndst[pos] = d;
}

// ---------------------------------------------------------------------------
// Fused layer kernel — NO per-thread segment loops.
// Block owns NB=32 consecutive nodes. For each relation r, the block's CSR
// positions [off[r*N+n0], off[r*N+n0+NB]) are one contiguous range (monotone
// off). All 256 threads sweep that range flat: coalesced eidx/ndst reads,
// one 16B fp16-row gather, 8 LDS atomicAdds into sAgg[node][r][ch].
// Then divide by cnt and run the dense transform (W/root broadcast from L1).
// ---------------------------------------------------------------------------
template <int DIN, int DOUT, bool RELU, bool OUT_HALF>
__global__ __launch_bounds__(256, 8) void rgcn_layer_kernel(
    const __half* __restrict__ tab, const int* __restrict__ cnt,
    const int* __restrict__ off, const int* __restrict__ eidx,
    const int* __restrict__ ndst, const float* __restrict__ W,
    const float* __restrict__ root, const float* __restrict__ bias,
    void* __restrict__ outp, int N) {
  constexpr int GRAN = DIN / 8;   // 16B fp16 granules per row (2 or 4)
  constexpr int NB = 32;          // nodes per block (N=100000 = 3125*32 exact)
  __shared__ float sAgg[NB][N_REL][DIN];
  __shared__ float sX[NB][DIN];
  const int tid = threadIdx.x;
  const int n0 = blockIdx.x * NB;

  // zero accumulators
  for (int i = tid; i < NB * N_REL * DIN; i += 256) (&sAgg[0][0][0])[i] = 0.f;
  // stage self rows
  if (tid < NB * GRAN) {
    int nl = tid / GRAN, g = tid % GRAN;
    int node = n0 + nl;
    if (node < N) {
      union { float4 f; __half2 h[4]; } u;
      u.f = ((const float4*)tab)[(long)node * GRAN + g];
      float* d = &sX[nl][g * 8];
#pragma unroll
      for (int k = 0; k < 4; k++) {
        float2 f2 = __half22float2(u.h[k]);
        d[2 * k] = f2.x;
        d[2 * k + 1] = f2.y;
      }
    }
  }
  __syncthreads();

  // ---- flat edge sweeps (uniform across block; no divergence) ----
  const int wid = tid >> 6, lane = tid & 63;
  const int gg = wid % GRAN;          // granule this wave handles
  const int chunk = wid / GRAN;       // position-chunk this wave handles
  constexpr int CHUNKS = 4 / GRAN;    // 2 (DIN16) or 1 (DIN32)
#pragma unroll
  for (int r = 0; r < N_REL; r++) {
    int nend = n0 + NB;
    if (nend > N) nend = N;
    const int pStart = off[r * N + n0];
    const int pEnd = off[r * N + nend];  // monotone; off[RN]=E sentinel
    for (int p0 = pStart + chunk * 64; p0 < pEnd; p0 += CHUNKS * 64) {
      const int p = p0 + lane;
      if (p < pEnd) {
        const int sidx = eidx[p];
        const int nl = ndst[p] - n0;
        union { float4 f; __half2 h[4]; } u;
        u.f = ((const float4*)tab)[(long)sidx * GRAN + gg];
        float* d = &sAgg[nl][r][gg * 8];
#pragma unroll
        for (int k = 0; k < 4; k++) {
          float2 f2 = __half22float2(u.h[k]);
          atomicAdd(&d[2 * k], f2.x);
          atomicAdd(&d[2 * k + 1], f2.y);
        }
      }
    }
  }
  __syncthreads();

  // ---- divide by counts ----
  if (tid < NB * N_REL) {
    const int nl = tid >> 2, r = tid & 3;
    const int node = n0 + nl;
    if (node < N) {
      const int c = cnt[r * N + node];
      const float ic = (c > 0) ? 1.f / (float)c : 0.f;
#pragma unroll
      for (int ch = 0; ch < DIN; ch++) sAgg[nl][r][ch] *= ic;
    }
  }
  __syncthreads();

  // ---- dense transform ----
  constexpr int NPP = 256 / DOUT;
  constexpr int PASSES = NB / NPP;
  const int oc = tid % DOUT;
  const int nj0 = tid / DOUT;
#pragma unroll
  for (int p = 0; p < PASSES; p++) {
    const int nj = nj0 + p * NPP;
    const int node2 = n0 + nj;
    if (node2 < N) {
      float acc = bias[oc];
#pragma unroll
      for (int k = 0; k < DIN; k++) acc += sX[nj][k] * root[k * DOUT + oc];
#pragma unroll
      for (int r = 0; r < N_REL; r++) {
#pragma unroll
        for (int k = 0; k < DIN; k++)
          acc += sAgg[nj][r][k] * W[(r * DIN + k) * DOUT + oc];
      }
      if (RELU) acc = fmaxf(acc, 0.f);
      if (OUT_HALF)
        ((__half*)outp)[(long)node2 * DOUT + oc] = __float2half(acc);
      else
        ((float*)outp)[(long)node2 * DOUT + oc] = acc;
    }
  }
}

// ---------------------------------------------------------------------------
// Host launch
// ---------------------------------------------------------------------------
static inline size_t align256(size_t v) { return (v + 255) & ~(size_t)255; }

extern "C" void kernel_launch(void* const* d_in, const int* in_sizes, int n_in,
                              void* d_out, int out_size, void* d_ws,
                              size_t ws_size, hipStream_t stream) {
  const int N = N_NODES;
  const int E = N_EDGES;
  const int RN = N_REL * N;
  const int nB = (RN + 255) / 256;  // 1563 scan blocks

  const float* x = (const float*)d_in[0];
  const int* edge_index = (const int*)d_in[1];
  const int* et = (const int*)d_in[2];
  const float* W1 = (const float*)d_in[3];
  const float* root1 = (const float*)d_in[4];
  const float* b1 = (const float*)d_in[5];
  const float* W2 = (const float*)d_in[6];
  const float* root2 = (const float*)d_in[7];
  const float* b2 = (const float*)d_in[8];
  const float* W3 = (const float*)d_in[9];
  const float* root3 = (const float*)d_in[10];
  const float* b3 = (const float*)d_in[11];

  const int* src = edge_index;      // edge_index[0]
  const int* dst = edge_index + E;  // edge_index[1]

  // Workspace carve-up (~29 MB)
  char* ws = (char*)d_ws;
  size_t o = 0;
  int* cnt = (int*)(ws + o);
  o = align256(o + (size_t)RN * 4);
  int* off = (int*)(ws + o);
  o = align256(o + (size_t)(RN + 1) * 4);
  int* cur = (int*)(ws + o);
  o = align256(o + (size_t)RN * 4);
  int* bsum = (int*)(ws + o);
  o = align256(o + (size_t)nB * 4);
  int* bbase = (int*)(ws + o);
  o = align256(o + (size_t)nB * 4);
  int* eidx = (int*)(ws + o);
  o = align256(o + (size_t)E * 4);
  int* ndst = (int*)(ws + o);
  o = align256(o + (size_t)E * 4);
  __half* xh = (__half*)(ws + o);
  o = align256(o + (size_t)N * 16 * 2);
  __half* h1 = (__half*)(ws + o);
  o = align256(o + (size_t)N * 16 * 2);
  __half* h2 = (__half*)(ws + o);
  o = align256(o + (size_t)N * 32 * 2);
  (void)ws_size;

  float* out = (float*)d_out;

  const int gridE = (E + 255) / 256;
  const int gridL = N / 32;  // 3125, exact

  // --- CSR build (deterministic monotone offsets) + fp16 x ---
  hipMemsetAsync(cnt, 0, (size_t)RN * 4, stream);
  cvt_kernel<<<(N * 16 / 4 + 255) / 256, 256, 0, stream>>>(x, xh, N * 16 / 4);
  count_kernel<<<gridE, 256, 0, stream>>>(dst, et, cnt, E, N);
  blocksum_kernel<<<nB, 256, 0, stream>>>(cnt, bsum, RN);
  scanb_kernel<<<1, 256, 0, stream>>>(bsum, bbase, nB);
  alloc_kernel<<<nB, 256, 0, stream>>>(cnt, bbase, off, cur, RN, E);
  fill_kernel<<<gridE, 256, 0, stream>>>(src, dst, et, cur, eidx, ndst, E, N);

  // --- layer 1: 16 -> 16, relu, fp16 out ---
  rgcn_layer_kernel<16, 16, true, true><<<gridL, 256, 0, stream>>>(
      xh, cnt, off, eidx, ndst, W1, root1, b1, h1, N);
  // --- layer 2: 16 -> 32, relu, fp16 out ---
  rgcn_layer_kernel<16, 32, true, true><<<gridL, 256, 0, stream>>>(
      h1, cnt, off, eidx, ndst, W2, root2, b2, h2, N);
  // --- layer 3: 32 -> 64, no relu, fp32 out ---
  rgcn_layer_kernel<32, 64, false, false><<<gridL, 256, 0, stream>>>(
      h2, cnt, off, eidx, ndst, W3, root3, b3, out, N);
}